// Round 2
// baseline (406.837 us; speedup 1.0000x reference)
//
#include <hip/hip_runtime.h>
#include <hip/hip_bf16.h>
#include <stdint.h>

// MultiHeadSelfAttention on 3D volume: B=2,C=256,H=8,P=32,X=Y=Z=48
// scores contract (p,z) per (b,x,y) -> 8x8; softmax over y (faithful torch bug);
// out einsum over m; all projections bf16 MFMA, score/softmax/einsum fp32.

#define S_TOT 110592   // 48*48*48
#define NXY2  1152     // 2304 (x,y) columns / 2 per workgroup

typedef unsigned short u16;
typedef __attribute__((ext_vector_type(8))) short bf16x8;
typedef __attribute__((ext_vector_type(4))) float f32x4;

__device__ __forceinline__ u16 f2b(float f){
  union { float f; uint32_t u; } v; v.f = f;
  uint32_t u = v.u;
  return (u16)((u + 0x7fffu + ((u >> 16) & 1u)) >> 16);   // RNE
}
__device__ __forceinline__ float b2f(u16 h){
  union { float f; uint32_t u; } v; v.u = ((uint32_t)h) << 16; return v.f;
}
__device__ __forceinline__ float u2f_lo(uint32_t u){
  union { float f; uint32_t u; } v; v.u = u << 16; return v.f;
}
__device__ __forceinline__ float u2f_hi(uint32_t u){
  union { float f; uint32_t u; } v; v.u = u & 0xffff0000u; return v.f;
}
__device__ __forceinline__ f32x4 mfma16(bf16x8 a, bf16x8 b, f32x4 c){
  return __builtin_amdgcn_mfma_f32_16x16x32_bf16(a, b, c, 0, 0, 0);
}

// ---------------- K0: weight prep -> bf16 images matching LDS chunk layout ---
// wqk: 8 chunks x [512 rows x 40 bf16] (rows 0-255 = wq, 256-511 = wk; 32 data + 8 pad)
// wv:  8 chunks x [256 x 40]   wo: 8 chunks x [256 x 40]
__global__ __launch_bounds__(256) void k_prep(
    const float* __restrict__ wq, const float* __restrict__ wk,
    const float* __restrict__ wv, const float* __restrict__ wo,
    u16* __restrict__ img)
{
  int idx = blockIdx.x * 256 + threadIdx.x;
  if (idx < 163840){
    int ck = idx / 20480, rem = idx % 20480;
    int r = rem / 40, i = rem % 40;
    float v = 0.f;
    if (i < 32){
      int c = ck * 32 + i;
      v = (r < 256) ? wq[r * 256 + c] : wk[(r - 256) * 256 + c];
    }
    img[idx] = f2b(v);
  } else if (idx < 245760){
    int l = idx - 163840;
    int ck = l / 10240, rem = l % 10240;
    int r = rem / 40, i = rem % 40;
    float v = (i < 32) ? wv[r * 256 + ck * 32 + i] : 0.f;
    img[idx] = f2b(v);
  } else if (idx < 327680){
    int l = idx - 245760;
    int ck = l / 10240, rem = l % 10240;
    int r = rem / 40, i = rem % 40;
    float v = (i < 32) ? wo[r * 256 + ck * 32 + i] : 0.f;
    img[idx] = f2b(v);
  }
}

// ---------------- K1: fused q,k projection + scores --------------------------
// grid (1152, 2), 512 threads (8 waves). Per wg: 96 spatial (= 2 full z-columns).
// LDS: xT [96][264 bf16] @0 (50688) | w dbuf 2x40960 @50688 -> 132608 total.
// Epilogue reuse: qk head-minor [512 rows][100 u16] @0 (102400).
#define K1_LDS 132608
__global__ __launch_bounds__(512, 2) void k_qk_scores(
    const float* __restrict__ x, const u16* __restrict__ wimg,
    const float* __restrict__ bq, const float* __restrict__ bk,
    float* __restrict__ scores)
{
  extern __shared__ char lds[];
  u16*  xT = (u16*)lds;                         // pitch 528 B
  uint4* w0 = (uint4*)(lds + 50688);
  uint4* w1 = (uint4*)(lds + 91648);

  const int tid  = threadIdx.x;
  const int wave = tid >> 6, lane = tid & 63;
  const int l15 = lane & 15, l4 = lane >> 4;
  const int xy2 = blockIdx.x, b = blockIdx.y;
  const int s0 = xy2 * 96;
  const float* xb = x + (size_t)b * 256 * S_TOT;

  // prefetch weight chunk 0 (2560 uint4 = 5/thread)
  uint4 wr[5];
  {
    const uint4* src = (const uint4*)wimg;
    #pragma unroll
    for (int i = 0; i < 5; i++) wr[i] = src[i * 512 + tid];
  }
  // stage x transposed -> xT[s][c], bf16
  #pragma unroll
  for (int it = 0; it < 12; it++){
    int e = it * 512 + tid;
    int s = e % 96, cq = e / 96;
    const float* px = xb + (size_t)cq * 4 * S_TOT + s0 + s;
    ushort4 u;
    u.x = f2b(px[0]);
    u.y = f2b(px[S_TOT]);
    u.z = f2b(px[2 * S_TOT]);
    u.w = f2b(px[3 * S_TOT]);
    *(ushort4*)((char*)xT + s * 528 + cq * 8) = u;
  }
  #pragma unroll
  for (int i = 0; i < 5; i++) w0[i * 512 + tid] = wr[i];
  __syncthreads();

  // accumulators: wave owns rows wave*64..+63 (waves 0-3 = q, 4-7 = k), 96 cols
  f32x4 acc[4][6];
  {
    const float* bias = (wave < 4) ? bq : bk;
    int rb = (wave & 3) * 64;
    #pragma unroll
    for (int fr = 0; fr < 4; fr++){
      f32x4 iv;
      #pragma unroll
      for (int j = 0; j < 4; j++) iv[j] = bias[rb + fr * 16 + l4 * 4 + j];
      #pragma unroll
      for (int fc = 0; fc < 6; fc++) acc[fr][fc] = iv;
    }
  }

  #pragma unroll
  for (int ck = 0; ck < 8; ck++){
    const uint4* wc = (ck & 1) ? w1 : w0;
    uint4*       wn = (ck & 1) ? w0 : w1;
    if (ck < 7){
      const uint4* src = (const uint4*)(wimg + (size_t)(ck + 1) * 20480);
      #pragma unroll
      for (int i = 0; i < 5; i++) wr[i] = src[i * 512 + tid];
    }
    bf16x8 af[4], bf[6];
    #pragma unroll
    for (int fr = 0; fr < 4; fr++){
      int row = wave * 64 + fr * 16 + l15;
      af[fr] = *(const bf16x8*)((const char*)wc + row * 80 + l4 * 16);
    }
    #pragma unroll
    for (int fc = 0; fc < 6; fc++){
      int col = fc * 16 + l15;
      bf[fc] = *(const bf16x8*)((const char*)xT + col * 528 + ck * 64 + l4 * 16);
    }
    #pragma unroll
    for (int fr = 0; fr < 4; fr++)
      #pragma unroll
      for (int fc = 0; fc < 6; fc++)
        acc[fr][fc] = mfma16(af[fr], bf[fc], acc[fr][fc]);
    if (ck < 7){
      #pragma unroll
      for (int i = 0; i < 5; i++) wn[i * 512 + tid] = wr[i];
    }
    __syncthreads();
  }

  // epilogue: q,k -> head-minor LDS (row = proj*256 + p*8 + head, pitch 100 u16)
  u16* qk = (u16*)lds;
  {
    int proj = wave >> 2;
    int rb = (wave & 3) * 64;
    #pragma unroll
    for (int fr = 0; fr < 4; fr++){
      #pragma unroll
      for (int j = 0; j < 4; j++){
        int o = rb + fr * 16 + l4 * 4 + j;
        int lrow = proj * 256 + (o & 31) * 8 + (o >> 5);
        #pragma unroll
        for (int fc = 0; fc < 6; fc++){
          int z = fc * 16 + l15;
          qk[lrow * 100 + z] = f2b(acc[fr][fc][j]);
        }
      }
    }
  }
  __syncthreads();

  // scores: wave = q-head n; lane: m = lane&7, g = lane>>3 (tile = g>>2, z-slice g&3)
  {
    const int n = wave;
    const int m = lane & 7;
    const int g = lane >> 3;
    const int tile = g >> 2;
    const int dwoff = tile * 24 + (g & 3) * 6;    // dwords: 48 bf16/tile, 12 bf16/slice
    const uint32_t* qku = (const uint32_t*)qk;
    float s = 0.f;
    for (int p = 0; p < 32; p++){
      const uint32_t* qd = qku + (p * 8 + n) * 50 + dwoff;
      const uint32_t* kd = qku + (256 + p * 8 + m) * 50 + dwoff;
      #pragma unroll
      for (int d = 0; d < 6; d++){
        uint32_t uq = qd[d], uk = kd[d];
        s = fmaf(u2f_lo(uq), u2f_lo(uk), s);
        s = fmaf(u2f_hi(uq), u2f_hi(uk), s);
      }
    }
    s += __shfl_xor(s, 8);
    s += __shfl_xor(s, 16);
    if ((lane & 24) == 0){
      int pair = (b * 8 + n) * 8 + m;
      scores[(size_t)pair * 2304 + xy2 * 2 + tile] = s * 0.17677669529663687f;
    }
  }
}

// ---------------- K2: softmax over y (rows = (b,n,m,x), 48 y each) -----------
__global__ __launch_bounds__(256) void k_softmax(
    const float* __restrict__ scores, float* __restrict__ attn)
{
  int row  = blockIdx.x * 4 + (threadIdx.x >> 6);
  int lane = threadIdx.x & 63;
  const float* src = scores + (size_t)row * 48;
  float v = (lane < 48) ? src[lane] : -1e30f;
  float m = v;
  #pragma unroll
  for (int off = 32; off; off >>= 1) m = fmaxf(m, __shfl_xor(m, off));
  float e = (lane < 48) ? __expf(v - m) : 0.f;
  float s = e;
  #pragma unroll
  for (int off = 32; off; off >>= 1) s += __shfl_xor(s, off);
  if (lane < 48) attn[(size_t)row * 48 + lane] = e / s;
}

// ---------------- K3: v projection (recomputed) + attn*v + wo GEMM -----------
// LDS: xT@0 (50688) | wv dbuf @50688,@71168 | then vlds[256][100]@0 (51200) |
//      outT [96][264]@51200 (50688) | wo dbuf @101888,@122368 | attn @142848
#define K3_LDS 143360
__global__ __launch_bounds__(512, 2) void k_out(
    const float* __restrict__ x, const u16* __restrict__ wvimg,
    const u16* __restrict__ woimg, const float* __restrict__ bv,
    const float* __restrict__ bo, const float* __restrict__ attn,
    float* __restrict__ out)
{
  extern __shared__ char lds[];
  u16*  xT = (u16*)lds;
  uint4* w0 = (uint4*)(lds + 50688);
  uint4* w1 = (uint4*)(lds + 71168);
  u16*  vlds = (u16*)lds;                       // [256][100] after v GEMM
  u16*  outT = (u16*)(lds + 51200);             // [96][264]
  uint4* q0 = (uint4*)(lds + 101888);
  uint4* q1 = (uint4*)(lds + 122368);
  float* atl = (float*)(lds + 142848);          // [2 tiles][64 pairs]

  const int tid  = threadIdx.x;
  const int wave = tid >> 6, lane = tid & 63;
  const int l15 = lane & 15, l4 = lane >> 4;
  const int xy2 = blockIdx.x, b = blockIdx.y;
  const int s0 = xy2 * 96;
  const float* xb = x + (size_t)b * 256 * S_TOT;

  if (tid < 128)
    atl[tid] = attn[(size_t)(b * 64 + (tid & 63)) * 2304 + xy2 * 2 + (tid >> 6)];

  // prefetch wv chunk 0 (1280 uint4)
  uint4 a0, a1, a2 = {0,0,0,0};
  {
    const uint4* src = (const uint4*)wvimg;
    a0 = src[tid]; a1 = src[512 + tid];
    if (tid < 256) a2 = src[1024 + tid];
  }
  #pragma unroll
  for (int it = 0; it < 12; it++){
    int e = it * 512 + tid;
    int s = e % 96, cq = e / 96;
    const float* px = xb + (size_t)cq * 4 * S_TOT + s0 + s;
    ushort4 u;
    u.x = f2b(px[0]);
    u.y = f2b(px[S_TOT]);
    u.z = f2b(px[2 * S_TOT]);
    u.w = f2b(px[3 * S_TOT]);
    *(ushort4*)((char*)xT + s * 528 + cq * 8) = u;
  }
  w0[tid] = a0; w0[512 + tid] = a1;
  if (tid < 256) w0[1024 + tid] = a2;
  __syncthreads();

  // v GEMM: wave owns rows wave*32..+31
  f32x4 vac[2][6];
  {
    #pragma unroll
    for (int fr = 0; fr < 2; fr++){
      f32x4 iv;
      #pragma unroll
      for (int j = 0; j < 4; j++) iv[j] = bv[wave * 32 + fr * 16 + l4 * 4 + j];
      #pragma unroll
      for (int fc = 0; fc < 6; fc++) vac[fr][fc] = iv;
    }
  }
  #pragma unroll
  for (int ck = 0; ck < 8; ck++){
    const uint4* wc = (ck & 1) ? w1 : w0;
    uint4*       wn = (ck & 1) ? w0 : w1;
    if (ck < 7){
      const uint4* src = (const uint4*)(wvimg + (size_t)(ck + 1) * 10240);
      a0 = src[tid]; a1 = src[512 + tid];
      if (tid < 256) a2 = src[1024 + tid];
    }
    bf16x8 af[2], bf[6];
    #pragma unroll
    for (int fr = 0; fr < 2; fr++){
      int row = wave * 32 + fr * 16 + l15;
      af[fr] = *(const bf16x8*)((const char*)wc + row * 80 + l4 * 16);
    }
    #pragma unroll
    for (int fc = 0; fc < 6; fc++){
      int col = fc * 16 + l15;
      bf[fc] = *(const bf16x8*)((const char*)xT + col * 528 + ck * 64 + l4 * 16);
    }
    #pragma unroll
    for (int fr = 0; fr < 2; fr++)
      #pragma unroll
      for (int fc = 0; fc < 6; fc++)
        vac[fr][fc] = mfma16(af[fr], bf[fc], vac[fr][fc]);
    if (ck < 7){
      wn[tid] = a0; wn[512 + tid] = a1;
      if (tid < 256) wn[1024 + tid] = a2;
    }
    __syncthreads();
  }

  // v epilogue -> vlds (channel-major, pitch 100 u16)
  #pragma unroll
  for (int fr = 0; fr < 2; fr++)
    #pragma unroll
    for (int j = 0; j < 4; j++){
      int o = wave * 32 + fr * 16 + l4 * 4 + j;
      #pragma unroll
      for (int fc = 0; fc < 6; fc++){
        int z = fc * 16 + l15;
        vlds[o * 100 + z] = f2b(vac[fr][fc][j]);
      }
    }
  // prefetch wo chunk 0
  uint4 p0, p1, p2 = {0,0,0,0};
  {
    const uint4* src = (const uint4*)woimg;
    p0 = src[tid]; p1 = src[512 + tid];
    if (tid < 256) p2 = src[1024 + tid];
  }
  __syncthreads();

  // out einsum (fp32): out[c][z] = sum_m attn[n(c),m] * v[m*32+p(c)][z] -> outT bf16
  #pragma unroll
  for (int it = 0; it < 12; it++){
    int e = it * 512 + tid;
    int z96 = e % 96, cq = e / 96;
    const float* at = atl + ((z96 >= 48) ? 64 : 0);
    ushort4 pk;
    #pragma unroll
    for (int i2 = 0; i2 < 4; i2++){
      int c = cq * 4 + i2;
      int hn = c >> 5, p = c & 31;
      float a = 0.f;
      #pragma unroll
      for (int m = 0; m < 8; m++)
        a = fmaf(at[hn * 8 + m], b2f(vlds[(m * 32 + p) * 100 + z96]), a);
      ((u16*)&pk)[i2] = f2b(a);
    }
    *(ushort4*)((char*)outT + z96 * 528 + cq * 8) = pk;
  }
  q0[tid] = p0; q0[512 + tid] = p1;
  if (tid < 256) q0[1024 + tid] = p2;
  __syncthreads();

  // wo GEMM
  f32x4 oac[2][6];
  {
    #pragma unroll
    for (int fr = 0; fr < 2; fr++){
      f32x4 iv;
      #pragma unroll
      for (int j = 0; j < 4; j++) iv[j] = bo[wave * 32 + fr * 16 + l4 * 4 + j];
      #pragma unroll
      for (int fc = 0; fc < 6; fc++) oac[fr][fc] = iv;
    }
  }
  #pragma unroll
  for (int ck = 0; ck < 8; ck++){
    const uint4* wc = (ck & 1) ? q1 : q0;
    uint4*       wn = (ck & 1) ? q0 : q1;
    if (ck < 7){
      const uint4* src = (const uint4*)(woimg + (size_t)(ck + 1) * 10240);
      p0 = src[tid]; p1 = src[512 + tid];
      if (tid < 256) p2 = src[1024 + tid];
    }
    bf16x8 af[2], bf[6];
    #pragma unroll
    for (int fr = 0; fr < 2; fr++){
      int row = wave * 32 + fr * 16 + l15;
      af[fr] = *(const bf16x8*)((const char*)wc + row * 80 + l4 * 16);
    }
    #pragma unroll
    for (int fc = 0; fc < 6; fc++){
      int col = fc * 16 + l15;
      bf[fc] = *(const bf16x8*)((const char*)outT + col * 528 + ck * 64 + l4 * 16);
    }
    #pragma unroll
    for (int fr = 0; fr < 2; fr++)
      #pragma unroll
      for (int fc = 0; fc < 6; fc++)
        oac[fr][fc] = mfma16(af[fr], bf[fc], oac[fr][fc]);
    if (ck < 7){
      wn[tid] = p0; wn[512 + tid] = p1;
      if (tid < 256) wn[1024 + tid] = p2;
    }
    __syncthreads();
  }

  // final store fp32
  #pragma unroll
  for (int fr = 0; fr < 2; fr++)
    #pragma unroll
    for (int fc = 0; fc < 6; fc++)
      #pragma unroll
      for (int j = 0; j < 4; j++){
        int o = wave * 32 + fr * 16 + l4 * 4 + j;
        int z = fc * 16 + l15;
        out[(size_t)(b * 256 + o) * S_TOT + s0 + z] = oac[fr][fc][j];
      }
}

// ---------------- launch ------------------------------------------------------
extern "C" void kernel_launch(void* const* d_in, const int* in_sizes, int n_in,
                              void* d_out, int out_size, void* d_ws, size_t ws_size,
                              hipStream_t stream) {
  (void)in_sizes; (void)n_in; (void)out_size; (void)ws_size;
  const float* x  = (const float*)d_in[0];
  const float* wq = (const float*)d_in[1];
  const float* bq = (const float*)d_in[2];
  const float* wk = (const float*)d_in[3];
  const float* bk = (const float*)d_in[4];
  const float* wv = (const float*)d_in[5];
  const float* bv = (const float*)d_in[6];
  const float* wo = (const float*)d_in[7];
  const float* bo = (const float*)d_in[8];
  float* out = (float*)d_out;

  char* ws = (char*)d_ws;
  u16*  wimg   = (u16*)ws;                       // wqk @0 (327680 B total imgs)
  u16*  wvimg  = (u16*)(ws + 327680);
  u16*  woimg  = (u16*)(ws + 491520);
  float* scores = (float*)(ws + 655360);         // 1179648 B
  float* attn   = (float*)(ws + 1835008);        // 1179648 B  (end ~2.9 MB)

  hipFuncSetAttribute((const void*)k_qk_scores,
                      hipFuncAttributeMaxDynamicSharedMemorySize, K1_LDS);
  hipFuncSetAttribute((const void*)k_out,
                      hipFuncAttributeMaxDynamicSharedMemorySize, K3_LDS);

  k_prep<<<1280, 256, 0, stream>>>(wq, wk, wv, wo, wimg);
  k_qk_scores<<<dim3(NXY2, 2), 512, K1_LDS, stream>>>(x, wimg, bq, bk, scores);
  k_softmax<<<1536, 256, 0, stream>>>(scores, attn);
  k_out<<<dim3(NXY2, 2), 512, K3_LDS, stream>>>(x, wvimg, woimg, bv, bo, attn, out);
}

// Round 3
// 303.954 us; speedup vs baseline: 1.3385x; 1.3385x over previous
//
#include <hip/hip_runtime.h>
#include <hip/hip_bf16.h>
#include <stdint.h>

// MultiHeadSelfAttention: B=2,C=256,H=8,P=32,X=Y=Z=48
// Per block: one (b,x,y) column = 48 z. Weights read from L2 (no LDS staging),
// barrier-free MFMA K-loops, XOR-swizzled LDS tiles (~2-way max conflicts).

#define S_TOT 110592   // 48*48*48
#define NBX   2304     // (x,y) columns

typedef unsigned short u16;
typedef __attribute__((ext_vector_type(8))) short bf16x8;
typedef __attribute__((ext_vector_type(4))) float f32x4;

__device__ __forceinline__ u16 f2b(float f){
  union { float f; uint32_t u; } v; v.f = f;
  uint32_t u = v.u;
  return (u16)((u + 0x7fffu + ((u >> 16) & 1u)) >> 16);   // RNE
}
__device__ __forceinline__ float b2f(u16 h){
  union { float f; uint32_t u; } v; v.u = ((uint32_t)h) << 16; return v.f;
}
__device__ __forceinline__ float u2f_lo(uint32_t u){
  union { float f; uint32_t u; } v; v.u = u << 16; return v.f;
}
__device__ __forceinline__ float u2f_hi(uint32_t u){
  union { float f; uint32_t u; } v; v.u = u & 0xffff0000u; return v.f;
}
__device__ __forceinline__ f32x4 mfma16(bf16x8 a, bf16x8 b, f32x4 c){
  return __builtin_amdgcn_mfma_f32_16x16x32_bf16(a, b, c, 0, 0, 0);
}

// ---------------- K0: weight prep -> tight bf16 images -----------------------
// wqk: 8 chunks x [512 rows x 32 bf16]  (rows 0-255 wq, 256-511 wk)  131072 u16
// wv : 8 chunks x [256 x 32]  65536 u16 @131072
// wo : 8 chunks x [256 x 32]  65536 u16 @196608
__global__ __launch_bounds__(256) void k_prep(
    const float* __restrict__ wq, const float* __restrict__ wk,
    const float* __restrict__ wv, const float* __restrict__ wo,
    u16* __restrict__ img)
{
  int idx = blockIdx.x * 256 + threadIdx.x;
  if (idx < 131072){
    int ck = idx >> 14, rem = idx & 16383;
    int r = rem >> 5, i = rem & 31;
    int c = ck * 32 + i;
    float v = (r < 256) ? wq[r * 256 + c] : wk[(r - 256) * 256 + c];
    img[idx] = f2b(v);
  } else if (idx < 196608){
    int l = idx - 131072;
    int ck = l >> 13, rem = l & 8191;
    int r = rem >> 5, i = rem & 31;
    img[idx] = f2b(wv[r * 256 + ck * 32 + i]);
  } else if (idx < 262144){
    int l = idx - 196608;
    int ck = l >> 13, rem = l & 8191;
    int r = rem >> 5, i = rem & 31;
    img[idx] = f2b(wo[r * 256 + ck * 32 + i]);
  }
}

// stage x -> xT [48 z][256 ch] bf16, pitch 512 B, 16B chunks XOR-swizzled by z&7
__device__ __forceinline__ void stage_x(const float* xb, int s0, int tid, u16* xT){
  #pragma unroll
  for (int it = 0; it < 3; it++){
    int e = it * 512 + tid;
    int z = e % 48, c16 = e / 48;                // c16: 16B chunk = 8 channels
    const float* px = xb + (size_t)(c16 * 8) * S_TOT + s0 + z;
    union { uint4 q; u16 h[8]; } u;
    #pragma unroll
    for (int i = 0; i < 8; i++) u.h[i] = f2b(px[(size_t)i * S_TOT]);
    *(uint4*)((char*)xT + z * 512 + ((c16 ^ (z & 7)) << 4)) = u.q;
  }
}

// ---------------- K1: q,k projection + scores --------------------------------
// LDS: xT 24576 @0 during GEMM; qk [512 rows][52 u16] @0 after (53248 B peak)
#define K1_LDS 53248
__global__ __launch_bounds__(512, 4) void k_qk_scores(
    const float* __restrict__ x, const u16* __restrict__ wimg,
    const float* __restrict__ bq, const float* __restrict__ bk,
    float* __restrict__ scores)
{
  extern __shared__ char lds[];
  u16* xT = (u16*)lds;
  u16* qk = (u16*)lds;   // [proj*256 + p*8 + head][52], pitch 26 dw

  const int tid  = threadIdx.x;
  const int wave = tid >> 6, lane = tid & 63;
  const int l15 = lane & 15, l4 = lane >> 4;
  const int bx = blockIdx.x, b = blockIdx.y;
  const int s0 = bx * 48;
  const float* xb = x + (size_t)b * 256 * S_TOT;

  stage_x(xb, s0, tid, xT);
  __syncthreads();

  const int proj = wave >> 2;            // 0=q (waves 0-3), 1=k (waves 4-7)
  const int rb = (wave & 3) * 64;        // row base within proj
  const float* bias = proj ? bk : bq;

  f32x4 acc[4][3];
  #pragma unroll
  for (int fr = 0; fr < 4; fr++){
    f32x4 iv;
    #pragma unroll
    for (int j = 0; j < 4; j++) iv[j] = bias[rb + fr * 16 + l4 * 4 + j];
    #pragma unroll
    for (int fc = 0; fc < 3; fc++) acc[fr][fc] = iv;
  }

  #pragma unroll
  for (int ck = 0; ck < 8; ck++){
    bf16x8 af[4], bfr[3];
    #pragma unroll
    for (int fr = 0; fr < 4; fr++){
      int row = wave * 64 + fr * 16 + l15;       // row within 512 (q|k)
      af[fr] = *(const bf16x8*)(wimg + ck * 16384 + row * 32 + l4 * 8);
    }
    #pragma unroll
    for (int fc = 0; fc < 3; fc++){
      int z = fc * 16 + l15;
      bfr[fc] = *(const bf16x8*)((char*)xT + z * 512 + (((ck * 4 + l4) ^ (l15 & 7)) << 4));
    }
    #pragma unroll
    for (int fr = 0; fr < 4; fr++)
      #pragma unroll
      for (int fc = 0; fc < 3; fc++)
        acc[fr][fc] = mfma16(af[fr], bfr[fc], acc[fr][fc]);
  }
  __syncthreads();

  // epilogue: head-minor rows (p*8+head) so score-phase k-reads spread banks
  #pragma unroll
  for (int fr = 0; fr < 4; fr++)
    #pragma unroll
    for (int j = 0; j < 4; j++){
      int o = rb + fr * 16 + l4 * 4 + j;         // channel 0..255 within proj
      int lrow = proj * 256 + (o & 31) * 8 + (o >> 5);
      #pragma unroll
      for (int fc = 0; fc < 3; fc++){
        int z = fc * 16 + l15;
        qk[lrow * 52 + z] = f2b(acc[fr][fc][j]);
      }
    }
  __syncthreads();

  // scores: wave = q-head n; lane: m = lane&7, g = lane>>3 (6 z = 3 dw per g)
  {
    const int n = wave, m = lane & 7, g = lane >> 3;
    const int dwoff = g * 3;
    const uint32_t* qku = (const uint32_t*)qk;
    float s = 0.f;
    for (int p = 0; p < 32; p++){
      const uint32_t* qd = qku + (p * 8 + n) * 26 + dwoff;
      const uint32_t* kd = qku + (256 + p * 8 + m) * 26 + dwoff;
      #pragma unroll
      for (int d = 0; d < 3; d++){
        uint32_t uq = qd[d], uk = kd[d];
        s = fmaf(u2f_lo(uq), u2f_lo(uk), s);
        s = fmaf(u2f_hi(uq), u2f_hi(uk), s);
      }
    }
    s += __shfl_xor(s, 8);
    s += __shfl_xor(s, 16);
    s += __shfl_xor(s, 32);
    if ((lane & 56) == 0)
      scores[(size_t)(b * 64 + n * 8 + m) * NBX + bx] = s * 0.17677669529663687f;
  }
}

// ---------------- K2: softmax over y ------------------------------------------
__global__ __launch_bounds__(256) void k_softmax(
    const float* __restrict__ scores, float* __restrict__ attn)
{
  int row  = blockIdx.x * 4 + (threadIdx.x >> 6);
  int lane = threadIdx.x & 63;
  const float* src = scores + (size_t)row * 48;
  float v = (lane < 48) ? src[lane] : -1e30f;
  float m = v;
  #pragma unroll
  for (int off = 32; off; off >>= 1) m = fmaxf(m, __shfl_xor(m, off));
  float e = (lane < 48) ? __expf(v - m) : 0.f;
  float s = e;
  #pragma unroll
  for (int off = 32; off; off >>= 1) s += __shfl_xor(s, off);
  if (lane < 48) attn[(size_t)row * 48 + lane] = e / s;
}

// ---------------- K3: v proj + attn*v + wo GEMM -------------------------------
// LDS: xT 24576 @0 | vl [48 z][256 ch] swz @24576 | outT @0 (reuse) | atl @49152
#define K3_LDS 49408
__global__ __launch_bounds__(512, 4) void k_out(
    const float* __restrict__ x, const u16* __restrict__ wvimg,
    const u16* __restrict__ woimg, const float* __restrict__ bv,
    const float* __restrict__ bo, const float* __restrict__ attn,
    float* __restrict__ out)
{
  extern __shared__ char lds[];
  u16* xT = (u16*)lds;
  u16* vl = (u16*)(lds + 24576);
  u16* oT = (u16*)lds;
  float* atl = (float*)(lds + 49152);

  const int tid  = threadIdx.x;
  const int wave = tid >> 6, lane = tid & 63;
  const int l15 = lane & 15, l4 = lane >> 4;
  const int bx = blockIdx.x, b = blockIdx.y;
  const int s0 = bx * 48;
  const float* xb = x + (size_t)b * 256 * S_TOT;

  if (tid < 64) atl[tid] = attn[(size_t)(b * 64 + tid) * NBX + bx];

  stage_x(xb, s0, tid, xT);
  __syncthreads();

  // ---- v GEMM: wave owns channels wave*32..+31
  f32x4 vac[2][3];
  #pragma unroll
  for (int fr = 0; fr < 2; fr++){
    f32x4 iv;
    #pragma unroll
    for (int j = 0; j < 4; j++) iv[j] = bv[wave * 32 + fr * 16 + l4 * 4 + j];
    #pragma unroll
    for (int fc = 0; fc < 3; fc++) vac[fr][fc] = iv;
  }
  #pragma unroll
  for (int ck = 0; ck < 8; ck++){
    bf16x8 af[2], bfr[3];
    #pragma unroll
    for (int fr = 0; fr < 2; fr++){
      int row = wave * 32 + fr * 16 + l15;
      af[fr] = *(const bf16x8*)(wvimg + ck * 8192 + row * 32 + l4 * 8);
    }
    #pragma unroll
    for (int fc = 0; fc < 3; fc++){
      int z = fc * 16 + l15;
      bfr[fc] = *(const bf16x8*)((char*)xT + z * 512 + (((ck * 4 + l4) ^ (l15 & 7)) << 4));
    }
    #pragma unroll
    for (int fr = 0; fr < 2; fr++)
      #pragma unroll
      for (int fc = 0; fc < 3; fc++)
        vac[fr][fc] = mfma16(af[fr], bfr[fc], vac[fr][fc]);
  }
  __syncthreads();

  // ---- v epilogue -> vl [z][ch] swizzled (ushort4 per fragment row-quad)
  #pragma unroll
  for (int fr = 0; fr < 2; fr++){
    int o0 = wave * 32 + fr * 16 + l4 * 4;
    #pragma unroll
    for (int fc = 0; fc < 3; fc++){
      int z = fc * 16 + l15;
      ushort4 u;
      u.x = f2b(vac[fr][fc][0]); u.y = f2b(vac[fr][fc][1]);
      u.z = f2b(vac[fr][fc][2]); u.w = f2b(vac[fr][fc][3]);
      *(ushort4*)((char*)vl + z * 512 + (((o0 >> 3) ^ (z & 7)) << 4) + (o0 & 7) * 2) = u;
    }
  }
  __syncthreads();

  // ---- einsum: out_ch c = c16*8+i; lanes span c16 so vl reads broadcast
  #pragma unroll
  for (int it = 0; it < 3; it++){
    int e = it * 512 + tid;
    int c16 = e & 31, z = e >> 5;
    int r = c16 & 3, hn = c16 >> 2;
    float a[8] = {0,0,0,0,0,0,0,0};
    #pragma unroll
    for (int m = 0; m < 8; m++){
      union { uint4 q; u16 h[8]; } v8;
      v8.q = *(const uint4*)((char*)vl + z * 512 + (((m * 4 + r) ^ (z & 7)) << 4));
      float am = atl[hn * 8 + m];
      #pragma unroll
      for (int i = 0; i < 8; i++) a[i] = fmaf(am, b2f(v8.h[i]), a[i]);
    }
    union { uint4 q; u16 h[8]; } pk;
    #pragma unroll
    for (int i = 0; i < 8; i++) pk.h[i] = f2b(a[i]);
    *(uint4*)((char*)oT + z * 512 + ((c16 ^ (z & 7)) << 4)) = pk.q;
  }
  __syncthreads();

  // ---- wo GEMM
  f32x4 oac[2][3];
  #pragma unroll
  for (int fr = 0; fr < 2; fr++){
    f32x4 iv;
    #pragma unroll
    for (int j = 0; j < 4; j++) iv[j] = bo[wave * 32 + fr * 16 + l4 * 4 + j];
    #pragma unroll
    for (int fc = 0; fc < 3; fc++) oac[fr][fc] = iv;
  }
  #pragma unroll
  for (int ck = 0; ck < 8; ck++){
    bf16x8 af[2], bfr[3];
    #pragma unroll
    for (int fr = 0; fr < 2; fr++){
      int row = wave * 32 + fr * 16 + l15;
      af[fr] = *(const bf16x8*)(woimg + ck * 8192 + row * 32 + l4 * 8);
    }
    #pragma unroll
    for (int fc = 0; fc < 3; fc++){
      int z = fc * 16 + l15;
      bfr[fc] = *(const bf16x8*)((char*)oT + z * 512 + (((ck * 4 + l4) ^ (l15 & 7)) << 4));
    }
    #pragma unroll
    for (int fr = 0; fr < 2; fr++)
      #pragma unroll
      for (int fc = 0; fc < 3; fc++)
        oac[fr][fc] = mfma16(af[fr], bfr[fc], oac[fr][fc]);
  }

  // ---- store fp32
  #pragma unroll
  for (int fr = 0; fr < 2; fr++)
    #pragma unroll
    for (int fc = 0; fc < 3; fc++)
      #pragma unroll
      for (int j = 0; j < 4; j++){
        int o = wave * 32 + fr * 16 + l4 * 4 + j;
        int z = fc * 16 + l15;
        out[(size_t)(b * 256 + o) * S_TOT + s0 + z] = oac[fr][fc][j];
      }
}

// ---------------- launch ------------------------------------------------------
extern "C" void kernel_launch(void* const* d_in, const int* in_sizes, int n_in,
                              void* d_out, int out_size, void* d_ws, size_t ws_size,
                              hipStream_t stream) {
  (void)in_sizes; (void)n_in; (void)out_size; (void)ws_size;
  const float* x  = (const float*)d_in[0];
  const float* wq = (const float*)d_in[1];
  const float* bq = (const float*)d_in[2];
  const float* wk = (const float*)d_in[3];
  const float* bk = (const float*)d_in[4];
  const float* wv = (const float*)d_in[5];
  const float* bv = (const float*)d_in[6];
  const float* wo = (const float*)d_in[7];
  const float* bo = (const float*)d_in[8];
  float* out = (float*)d_out;

  char* ws = (char*)d_ws;
  u16*  wimg   = (u16*)ws;                    // 262144 u16 = 524288 B
  u16*  wvimg  = wimg + 131072;
  u16*  woimg  = wimg + 196608;
  float* scores = (float*)(ws + 524288);      // 128*2304*4 = 1179648 B
  float* attn   = (float*)(ws + 1703936);     // 1179648 B (end ~2.9 MB)

  k_prep<<<1024, 256, 0, stream>>>(wq, wk, wv, wo, wimg);
  k_qk_scores<<<dim3(NBX, 2), 512, K1_LDS, stream>>>(x, wimg, bq, bk, scores);
  k_softmax<<<1536, 256, 0, stream>>>(scores, attn);
  k_out<<<dim3(NBX, 2), 512, K3_LDS, stream>>>(x, wvimg, woimg, bv, bo, attn, out);
}